// Round 4
// baseline (89.836 us; speedup 1.0000x reference)
//
#include <hip/hip_runtime.h>

typedef __attribute__((ext_vector_type(8))) short bf16x8;
typedef __attribute__((ext_vector_type(4))) float f32x4;

// ---------- helpers ----------

__device__ __forceinline__ unsigned short f2bf(float f) {
    unsigned int u = __builtin_bit_cast(unsigned int, f);
    u += 0x7fffu + ((u >> 16) & 1u);
    return (unsigned short)(u >> 16);
}

__device__ __forceinline__ float bf2f(unsigned short s) {
    return __builtin_bit_cast(float, (unsigned int)s << 16);
}

__device__ __forceinline__ void g2lds16(const unsigned short* g, unsigned short* l) {
    __builtin_amdgcn_global_load_lds(
        (const __attribute__((address_space(1))) unsigned int*)g,
        (__attribute__((address_space(3))) unsigned int*)l, 16, 0, 0);
}

// ---------- pack x, Wq, Wk -> bf16; also zero the ready counters ----------

__global__ __launch_bounds__(256)
void pack3_kernel(const float* __restrict__ x, const float* __restrict__ wq,
                  const float* __restrict__ wk, unsigned short* __restrict__ xb,
                  unsigned short* __restrict__ wqk, int* __restrict__ ready,
                  int n4x, int n4w) {
    int i = blockIdx.x * 256 + threadIdx.x;
    if (blockIdx.x == 0 && threadIdx.x < 64) ready[threadIdx.x] = 0;
    const float* src; unsigned short* dst; int idx;
    if (i < n4x)            { src = x;  dst = xb;  idx = i; }
    else if (i < n4x + n4w) { src = wq; dst = wqk; idx = i - n4x; }
    else                    { src = wk; dst = wqk + (size_t)n4w * 4; idx = i - n4x - n4w; }
    float4 v = reinterpret_cast<const float4*>(src)[idx];
    union { unsigned short s[4]; uint2 u; } o;
    o.s[0] = f2bf(v.x); o.s[1] = f2bf(v.y); o.s[2] = f2bf(v.z); o.s[3] = f2bf(v.w);
    reinterpret_cast<uint2*>(dst)[idx] = o.u;
}

// ---------- vd[b*T+j] = dot(xb[b,j,:], Wv[j,:]) + bv[j] ----------

__global__ __launch_bounds__(256)
void vdiag_kernel(const unsigned short* __restrict__ xb, const float* __restrict__ Wv,
                  const float* __restrict__ bv, float* __restrict__ vd) {
    int w = blockIdx.x * 4 + (threadIdx.x >> 6);
    int lane = threadIdx.x & 63;
    int b = w >> 10, j = w & 1023;
    const unsigned short* xr = xb + (size_t)(b * 1024 + j) * 1024;
    const float* wr = Wv + (size_t)j * 1024;
    float s = 0.f;
    #pragma unroll
    for (int e = 0; e < 2; ++e) {
        int base = e * 512 + lane * 8;
        bf16x8 xv = *reinterpret_cast<const bf16x8*>(xr + base);
        float4 w0 = *reinterpret_cast<const float4*>(wr + base);
        float4 w1 = *reinterpret_cast<const float4*>(wr + base + 4);
        s = fmaf(bf2f((unsigned short)xv[0]), w0.x, s);
        s = fmaf(bf2f((unsigned short)xv[1]), w0.y, s);
        s = fmaf(bf2f((unsigned short)xv[2]), w0.z, s);
        s = fmaf(bf2f((unsigned short)xv[3]), w0.w, s);
        s = fmaf(bf2f((unsigned short)xv[4]), w1.x, s);
        s = fmaf(bf2f((unsigned short)xv[5]), w1.y, s);
        s = fmaf(bf2f((unsigned short)xv[6]), w1.z, s);
        s = fmaf(bf2f((unsigned short)xv[7]), w1.w, s);
    }
    #pragma unroll
    for (int off = 32; off; off >>= 1) s += __shfl_down(s, off, 64);
    if (lane == 0) vd[w] = s + bv[j];
}

// ---------- NT GEMM, 128x128 tile, 2-phase double-buffered LDS ----------
// MODE 0: A=xb (Mx1024), B=wqk (2048x1024). col<1024 -> qb (relu+bq),
//         col>=1024 -> kb (relu+bk). bf16 outputs.
// MODE 1: A=qb[z], B=kb[z]. Computes num = C(t,j)*vd*QK in regs, publishes
//         denom partials to dpart, flag-syncs the row stripe across the 8
//         column blocks (all 256 blocks co-resident), then writes
//         out = num/denom (f32) directly. No num round trip through HBM.

template<int MODE>
__global__ __launch_bounds__(256, 2)
void gemm_kernel(const unsigned short* __restrict__ A, const unsigned short* __restrict__ Bm,
                 unsigned short* __restrict__ qb, unsigned short* __restrict__ kb,
                 const float* __restrict__ bq, const float* __restrict__ bk,
                 float* __restrict__ out, const float* __restrict__ vd,
                 float* __restrict__ dpart, int* __restrict__ ready,
                 const float* __restrict__ gammap, int K, int Mtot) {
    __shared__ unsigned short lA[2][128 * 32];
    __shared__ unsigned short lB[2][128 * 32];

    const int tid = threadIdx.x;
    const int lane = tid & 63;
    const int wid = tid >> 6;
    const int wr = wid >> 1, wc = wid & 1;
    const int tileM = blockIdx.y * 128, tileN = blockIdx.x * 128;

    const long bsAB = (MODE == 1) ? (long)1024 * 1024 : 0;
    const unsigned short* Ab = A + blockIdx.z * bsAB;
    const unsigned short* Bb = Bm + blockIdx.z * bsAB;

    const int r0 = tid >> 2;
    const int r1 = (tid + 256) >> 2;
    const int cc = (tid & 3) * 8;
    const int frow = lane & 15;
    const int fk = (lane >> 4) * 8;

    f32x4 acc[4][4];
    #pragma unroll
    for (int m = 0; m < 4; ++m)
        #pragma unroll
        for (int n = 0; n < 4; ++n)
            acc[m][n] = (f32x4){0.f, 0.f, 0.f, 0.f};

    auto stage = [&](int buf, int k0) {
        g2lds16(Ab + (size_t)(tileM + r0) * K + (k0 + cc), &lA[buf][tid * 8]);
        g2lds16(Ab + (size_t)(tileM + r1) * K + (k0 + cc), &lA[buf][2048 + tid * 8]);
        g2lds16(Bb + (size_t)(tileN + r0) * K + (k0 + cc), &lB[buf][tid * 8]);
        g2lds16(Bb + (size_t)(tileN + r1) * K + (k0 + cc), &lB[buf][2048 + tid * 8]);
    };

    stage(0, 0);
    __syncthreads();
    int cur = 0;
    for (int k0 = 0; k0 < K; k0 += 32) {
        if (k0 + 32 < K) stage(cur ^ 1, k0 + 32);   // prefetch next tile

        bf16x8 af[4], bfr[4];
        #pragma unroll
        for (int m = 0; m < 4; ++m)
            af[m] = *reinterpret_cast<const bf16x8*>(&lA[cur][(wr * 64 + m * 16 + frow) * 32 + fk]);
        #pragma unroll
        for (int n = 0; n < 4; ++n)
            bfr[n] = *reinterpret_cast<const bf16x8*>(&lB[cur][(wc * 64 + n * 16 + frow) * 32 + fk]);

        #pragma unroll
        for (int m = 0; m < 4; ++m)
            #pragma unroll
            for (int n = 0; n < 4; ++n)
                acc[m][n] = __builtin_amdgcn_mfma_f32_16x16x32_bf16(af[m], bfr[n], acc[m][n], 0, 0, 0);

        __syncthreads();
        cur ^= 1;
    }

    // C/D fragment layout: col = lane&15, row = (lane>>4)*4 + i
    const int orow = (lane >> 4) * 4;
    const int ocol = lane & 15;

    if constexpr (MODE == 0) {
        const bool isQ = tileN < 1024;
        unsigned short* Cq = isQ ? qb : kb;
        const float* bias = isQ ? bq : bk;
        const int cb = tileN - (isQ ? 0 : 1024);
        #pragma unroll
        for (int n = 0; n < 4; ++n) {
            int col = cb + wc * 64 + n * 16 + ocol;
            float bia = bias[col];
            #pragma unroll
            for (int m = 0; m < 4; ++m) {
                #pragma unroll
                for (int i = 0; i < 4; ++i) {
                    int row = tileM + wr * 64 + m * 16 + orow + i;
                    float v = acc[m][n][i] + bia;
                    Cq[(size_t)row * 1024 + col] = f2bf(v > 0.f ? v : 0.f);
                }
            }
        }
    } else {
        float* ob = out + (size_t)blockIdx.z * 1024 * 1024;
        const float* vdb = vd + blockIdx.z * 1024;
        const float g = gammap[0];
        const float l2g = log2f(g);
        const float inv1mg = 1.f / (1.f - g);
        const float c1 = g * inv1mg;

        int jcol[4]; float gj[4], vdv[4];
        #pragma unroll
        for (int n = 0; n < 4; ++n) {
            jcol[n] = tileN + wc * 64 + n * 16 + ocol;
            gj[n] = exp2f((float)jcol[n] * l2g);
            vdv[n] = vdb[jcol[n]];
        }

        // pass 1: denom partials; overwrite acc with numerator product C*vd*QK
        #pragma unroll
        for (int m = 0; m < 4; ++m) {
            #pragma unroll
            for (int i = 0; i < 4; ++i) {
                int t = tileM + wr * 64 + m * 16 + orow + i;
                float gt = exp2f((float)t * l2g);
                float ctf = (1.f - g * gt) * inv1mg;
                float s = 0.f;
                #pragma unroll
                for (int n = 0; n < 4; ++n) {
                    int j = jcol[n];
                    float Cfut = exp2f((float)(j - t) * l2g) * ctf;        // j > t
                    float Cpast = (float)(t - j + 1) + c1 * (1.f - gj[n]); // j <= t
                    float Cw = (j <= t) ? Cpast : Cfut;
                    float v = acc[m][n][i];
                    s += Cw * v;
                    acc[m][n][i] = Cw * vdv[n] * v;
                }
                s += __shfl_xor(s, 1, 64);
                s += __shfl_xor(s, 2, 64);
                s += __shfl_xor(s, 4, 64);
                s += __shfl_xor(s, 8, 64);
                if ((lane & 15) == 0)
                    dpart[(size_t)(blockIdx.x * 2 + wc) * Mtot + blockIdx.z * 1024 + t] = s;
            }
        }

        // signal: this block's partials are published
        const int stripe = blockIdx.z * 8 + blockIdx.y;
        __syncthreads();                       // all warps' dpart stores issued
        if (tid == 0) {
            __threadfence();                   // release: push stores device-wide
            atomicAdd(&ready[stripe], 1);      // device-scope by default
            // wait for all 8 column blocks of this row stripe
            while (__hip_atomic_load(&ready[stripe], __ATOMIC_ACQUIRE,
                                     __HIP_MEMORY_SCOPE_AGENT) < 8)
                __builtin_amdgcn_s_sleep(1);
            __threadfence();                   // acquire: invalidate stale caches
        }
        __syncthreads();

        // denominators for this block's 128 rows (fixed-order sum: deterministic)
        float* inv_s = reinterpret_cast<float*>(lA);  // LDS reuse
        if (tid < 128) {
            float dsum = 1e-6f;
            #pragma unroll
            for (int p = 0; p < 16; ++p)
                dsum += dpart[(size_t)p * Mtot + blockIdx.z * 1024 + tileM + tid];
            inv_s[tid] = 1.f / dsum;
        }
        __syncthreads();

        // pass 2: out = num / denom
        #pragma unroll
        for (int m = 0; m < 4; ++m) {
            #pragma unroll
            for (int i = 0; i < 4; ++i) {
                int tl = wr * 64 + m * 16 + orow + i;
                float inv = inv_s[tl];
                size_t rowoff = (size_t)(tileM + tl) * 1024;
                #pragma unroll
                for (int n = 0; n < 4; ++n)
                    ob[rowoff + jcol[n]] = acc[m][n][i] * inv;
            }
        }
    }
}

// ---------- launch ----------

extern "C" void kernel_launch(void* const* d_in, const int* in_sizes, int n_in,
                              void* d_out, int out_size, void* d_ws, size_t ws_size,
                              hipStream_t stream) {
    const float* x     = (const float*)d_in[0];
    const float* gamma = (const float*)d_in[1];
    const float* Wq    = (const float*)d_in[2];
    const float* bq    = (const float*)d_in[3];
    const float* Wk    = (const float*)d_in[4];
    const float* bk    = (const float*)d_in[5];
    const float* Wv    = (const float*)d_in[6];
    const float* bv    = (const float*)d_in[7];
    float* out = (float*)d_out;

    const int D = 1024, T = 1024;
    const int B = in_sizes[0] / (T * D);
    const int M = B * T;  // 4096

    char* ws = (char*)d_ws;
    size_t off = 0;
    unsigned short* xb  = (unsigned short*)(ws + off); off += (size_t)M * D * 2;      // 8 MB
    unsigned short* wqk = (unsigned short*)(ws + off); off += (size_t)2 * D * D * 2;  // 4 MB
    unsigned short* qb  = (unsigned short*)(ws + off); off += (size_t)M * D * 2;      // 8 MB
    unsigned short* kb  = (unsigned short*)(ws + off); off += (size_t)M * D * 2;      // 8 MB
    float* vd    = (float*)(ws + off); off += (size_t)M * 4;                          // 16 KB
    float* dpart = (float*)(ws + off); off += (size_t)16 * M * 4;                     // 256 KB
    int* ready   = (int*)(ws + off);   off += 64 * 4;

    const int n4x = M * D / 4, n4w = D * D / 4;

    // 1. pack x, Wq, Wk -> bf16; zero ready flags
    pack3_kernel<<<dim3((n4x + 2 * n4w) / 256), 256, 0, stream>>>(
        x, Wq, Wk, xb, wqk, ready, n4x, n4w);

    // 2. v diagonal (reads bf16 xb)
    vdiag_kernel<<<dim3(M / 4), 256, 0, stream>>>(xb, Wv, bv, vd);

    // 3. q = relu(x Wq^T + bq), k = relu(x Wk^T + bk) in one GEMM (N = 2048)
    gemm_kernel<0><<<dim3(2048 / 128, M / 128, 1), 256, 0, stream>>>(
        xb, wqk, qb, kb, bq, bk, nullptr, nullptr, nullptr, nullptr, nullptr, D, M);

    // 4. QK GEMM fused with denom flag-sync and final scale -> out (f32)
    gemm_kernel<1><<<dim3(T / 128, T / 128, B), 256, 0, stream>>>(
        qb, kb, nullptr, nullptr, nullptr, nullptr, out, vd, dpart, ready, gamma, D, M);
}

// Round 5
// 84.400 us; speedup vs baseline: 1.0644x; 1.0644x over previous
//
#include <hip/hip_runtime.h>

typedef __attribute__((ext_vector_type(8))) short bf16x8;
typedef __attribute__((ext_vector_type(4))) float f32x4;

// ---------- helpers ----------

__device__ __forceinline__ unsigned short f2bf(float f) {
    unsigned int u = __builtin_bit_cast(unsigned int, f);
    u += 0x7fffu + ((u >> 16) & 1u);
    return (unsigned short)(u >> 16);
}

__device__ __forceinline__ float bf2f(unsigned short s) {
    return __builtin_bit_cast(float, (unsigned int)s << 16);
}

__device__ __forceinline__ void g2lds16(const unsigned short* g, unsigned short* l) {
    __builtin_amdgcn_global_load_lds(
        (const __attribute__((address_space(1))) unsigned int*)g,
        (__attribute__((address_space(3))) unsigned int*)l, 16, 0, 0);
}

// ---------- pack x, Wq, Wk -> bf16 in one dispatch ----------

__global__ __launch_bounds__(256)
void pack3_kernel(const float* __restrict__ x, const float* __restrict__ wq,
                  const float* __restrict__ wk, unsigned short* __restrict__ xb,
                  unsigned short* __restrict__ wqk, int n4x, int n4w) {
    int i = blockIdx.x * 256 + threadIdx.x;
    const float* src; unsigned short* dst; int idx;
    if (i < n4x)            { src = x;  dst = xb;  idx = i; }
    else if (i < n4x + n4w) { src = wq; dst = wqk; idx = i - n4x; }
    else                    { src = wk; dst = wqk + (size_t)n4w * 4; idx = i - n4x - n4w; }
    float4 v = reinterpret_cast<const float4*>(src)[idx];
    union { unsigned short s[4]; uint2 u; } o;
    o.s[0] = f2bf(v.x); o.s[1] = f2bf(v.y); o.s[2] = f2bf(v.z); o.s[3] = f2bf(v.w);
    reinterpret_cast<uint2*>(dst)[idx] = o.u;
}

// ---------- vd[b*T+j] = dot(xb[b,j,:], Wv[j,:]) + bv[j] ----------

__global__ __launch_bounds__(256)
void vdiag_kernel(const unsigned short* __restrict__ xb, const float* __restrict__ Wv,
                  const float* __restrict__ bv, float* __restrict__ vd) {
    int w = blockIdx.x * 4 + (threadIdx.x >> 6);
    int lane = threadIdx.x & 63;
    int b = w >> 10, j = w & 1023;
    const unsigned short* xr = xb + (size_t)(b * 1024 + j) * 1024;
    const float* wr = Wv + (size_t)j * 1024;
    float s = 0.f;
    #pragma unroll
    for (int e = 0; e < 2; ++e) {
        int base = e * 512 + lane * 8;
        bf16x8 xv = *reinterpret_cast<const bf16x8*>(xr + base);
        float4 w0 = *reinterpret_cast<const float4*>(wr + base);
        float4 w1 = *reinterpret_cast<const float4*>(wr + base + 4);
        s = fmaf(bf2f((unsigned short)xv[0]), w0.x, s);
        s = fmaf(bf2f((unsigned short)xv[1]), w0.y, s);
        s = fmaf(bf2f((unsigned short)xv[2]), w0.z, s);
        s = fmaf(bf2f((unsigned short)xv[3]), w0.w, s);
        s = fmaf(bf2f((unsigned short)xv[4]), w1.x, s);
        s = fmaf(bf2f((unsigned short)xv[5]), w1.y, s);
        s = fmaf(bf2f((unsigned short)xv[6]), w1.z, s);
        s = fmaf(bf2f((unsigned short)xv[7]), w1.w, s);
    }
    #pragma unroll
    for (int off = 32; off; off >>= 1) s += __shfl_down(s, off, 64);
    if (lane == 0) vd[w] = s + bv[j];
}

// ---------- q/k GEMM: 256x128 tile, 512 threads (8 waves), 2-phase dbuf ----------
// A = xb (M x 1024), B = wqk (2048 x 1024), NT. col<1024 -> qb (relu+bq),
// col>=1024 -> kb (relu+bk), bf16 out. Grid (2048/128, M/256) = 16 x 16.

__global__ __launch_bounds__(512, 1)
void gemm_qk_kernel(const unsigned short* __restrict__ A, const unsigned short* __restrict__ Bm,
                    unsigned short* __restrict__ qb, unsigned short* __restrict__ kb,
                    const float* __restrict__ bq, const float* __restrict__ bk, int K) {
    __shared__ unsigned short lA[2][256 * 32];
    __shared__ unsigned short lB[2][128 * 32];

    const int tid = threadIdx.x;
    const int lane = tid & 63;
    const int wid = tid >> 6;           // 0..7
    const int wr = wid >> 1;            // 0..3 (row 64-stripe)
    const int wc = wid & 1;             // 0..1 (col 64-stripe)
    const int tileM = blockIdx.y * 256, tileN = blockIdx.x * 128;

    // staging: element idx e -> row e>>2 (4 slots of 8 per row), col (tid&3)*8
    const int rA0 = tid >> 2;           // rows 0..127
    const int rA1 = (tid + 512) >> 2;   // rows 128..255
    const int rB  = tid >> 2;           // rows 0..127
    const int cc  = (tid & 3) * 8;
    const int frow = lane & 15;
    const int fk = (lane >> 4) * 8;

    f32x4 acc[4][4];
    #pragma unroll
    for (int m = 0; m < 4; ++m)
        #pragma unroll
        for (int n = 0; n < 4; ++n)
            acc[m][n] = (f32x4){0.f, 0.f, 0.f, 0.f};

    auto stage = [&](int buf, int k0) {
        g2lds16(A + (size_t)(tileM + rA0) * K + (k0 + cc), &lA[buf][tid * 8]);
        g2lds16(A + (size_t)(tileM + rA1) * K + (k0 + cc), &lA[buf][4096 + tid * 8]);
        g2lds16(Bm + (size_t)(tileN + rB) * K + (k0 + cc), &lB[buf][tid * 8]);
    };

    stage(0, 0);
    __syncthreads();
    int cur = 0;
    for (int k0 = 0; k0 < K; k0 += 32) {
        if (k0 + 32 < K) stage(cur ^ 1, k0 + 32);

        bf16x8 af[4], bfr[4];
        #pragma unroll
        for (int m = 0; m < 4; ++m)
            af[m] = *reinterpret_cast<const bf16x8*>(&lA[cur][(wr * 64 + m * 16 + frow) * 32 + fk]);
        #pragma unroll
        for (int n = 0; n < 4; ++n)
            bfr[n] = *reinterpret_cast<const bf16x8*>(&lB[cur][(wc * 64 + n * 16 + frow) * 32 + fk]);

        #pragma unroll
        for (int m = 0; m < 4; ++m)
            #pragma unroll
            for (int n = 0; n < 4; ++n)
                acc[m][n] = __builtin_amdgcn_mfma_f32_16x16x32_bf16(af[m], bfr[n], acc[m][n], 0, 0, 0);

        __syncthreads();
        cur ^= 1;
    }

    const int orow = (lane >> 4) * 4;
    const int ocol = lane & 15;
    const bool isQ = tileN < 1024;
    unsigned short* Cq = isQ ? qb : kb;
    const float* bias = isQ ? bq : bk;
    const int cb = tileN - (isQ ? 0 : 1024);

    #pragma unroll
    for (int n = 0; n < 4; ++n) {
        int col = cb + wc * 64 + n * 16 + ocol;
        float bia = bias[col];
        #pragma unroll
        for (int m = 0; m < 4; ++m) {
            #pragma unroll
            for (int i = 0; i < 4; ++i) {
                int row = tileM + wr * 64 + m * 16 + orow + i;
                float v = acc[m][n][i] + bia;
                Cq[(size_t)row * 1024 + col] = f2bf(v > 0.f ? v : 0.f);
            }
        }
    }
}

// ---------- QK GEMM (per batch) fused with C-weight/vd: 128x128 tile ----------
// A = qb[z], B = kb[z]. Writes num' = C(t,j)*vd*QK as bf16 to nmb[z], denom
// partials to dpart[(bx*2+wc)*Mtot + z*1024 + t].

__global__ __launch_bounds__(256, 2)
void gemm_attn_kernel(const unsigned short* __restrict__ A, const unsigned short* __restrict__ Bm,
                      unsigned short* __restrict__ nmb, const float* __restrict__ vd,
                      float* __restrict__ dpart, const float* __restrict__ gammap,
                      int K, int Mtot) {
    __shared__ unsigned short lA[2][128 * 32];
    __shared__ unsigned short lB[2][128 * 32];

    const int tid = threadIdx.x;
    const int lane = tid & 63;
    const int wid = tid >> 6;
    const int wr = wid >> 1, wc = wid & 1;
    const int tileM = blockIdx.y * 128, tileN = blockIdx.x * 128;

    const unsigned short* Ab = A + (size_t)blockIdx.z * 1024 * 1024;
    const unsigned short* Bb = Bm + (size_t)blockIdx.z * 1024 * 1024;

    const int r0 = tid >> 2;
    const int r1 = (tid + 256) >> 2;
    const int cc = (tid & 3) * 8;
    const int frow = lane & 15;
    const int fk = (lane >> 4) * 8;

    f32x4 acc[4][4];
    #pragma unroll
    for (int m = 0; m < 4; ++m)
        #pragma unroll
        for (int n = 0; n < 4; ++n)
            acc[m][n] = (f32x4){0.f, 0.f, 0.f, 0.f};

    auto stage = [&](int buf, int k0) {
        g2lds16(Ab + (size_t)(tileM + r0) * K + (k0 + cc), &lA[buf][tid * 8]);
        g2lds16(Ab + (size_t)(tileM + r1) * K + (k0 + cc), &lA[buf][2048 + tid * 8]);
        g2lds16(Bb + (size_t)(tileN + r0) * K + (k0 + cc), &lB[buf][tid * 8]);
        g2lds16(Bb + (size_t)(tileN + r1) * K + (k0 + cc), &lB[buf][2048 + tid * 8]);
    };

    stage(0, 0);
    __syncthreads();
    int cur = 0;
    for (int k0 = 0; k0 < K; k0 += 32) {
        if (k0 + 32 < K) stage(cur ^ 1, k0 + 32);

        bf16x8 af[4], bfr[4];
        #pragma unroll
        for (int m = 0; m < 4; ++m)
            af[m] = *reinterpret_cast<const bf16x8*>(&lA[cur][(wr * 64 + m * 16 + frow) * 32 + fk]);
        #pragma unroll
        for (int n = 0; n < 4; ++n)
            bfr[n] = *reinterpret_cast<const bf16x8*>(&lB[cur][(wc * 64 + n * 16 + frow) * 32 + fk]);

        #pragma unroll
        for (int m = 0; m < 4; ++m)
            #pragma unroll
            for (int n = 0; n < 4; ++n)
                acc[m][n] = __builtin_amdgcn_mfma_f32_16x16x32_bf16(af[m], bfr[n], acc[m][n], 0, 0, 0);

        __syncthreads();
        cur ^= 1;
    }

    const int orow = (lane >> 4) * 4;
    const int ocol = lane & 15;

    unsigned short* ob = nmb + (size_t)blockIdx.z * 1024 * 1024;
    const float* vdb = vd + blockIdx.z * 1024;
    const float g = gammap[0];
    const float l2g = log2f(g);
    const float inv1mg = 1.f / (1.f - g);
    const float c1 = g * inv1mg;

    int jcol[4]; float gj[4], vdv[4];
    #pragma unroll
    for (int n = 0; n < 4; ++n) {
        jcol[n] = tileN + wc * 64 + n * 16 + ocol;
        gj[n] = exp2f((float)jcol[n] * l2g);
        vdv[n] = vdb[jcol[n]];
    }

    #pragma unroll
    for (int m = 0; m < 4; ++m) {
        #pragma unroll
        for (int i = 0; i < 4; ++i) {
            int t = tileM + wr * 64 + m * 16 + orow + i;
            float gt = exp2f((float)t * l2g);
            float ctf = (1.f - g * gt) * inv1mg;
            float s = 0.f;
            #pragma unroll
            for (int n = 0; n < 4; ++n) {
                int j = jcol[n];
                float Cfut = exp2f((float)(j - t) * l2g) * ctf;        // j > t
                float Cpast = (float)(t - j + 1) + c1 * (1.f - gj[n]); // j <= t
                float Cw = (j <= t) ? Cpast : Cfut;
                float v = acc[m][n][i];
                s += Cw * v;
                ob[(size_t)t * 1024 + j] = f2bf(Cw * vdv[n] * v);
            }
            s += __shfl_xor(s, 1, 64);
            s += __shfl_xor(s, 2, 64);
            s += __shfl_xor(s, 4, 64);
            s += __shfl_xor(s, 8, 64);
            if ((lane & 15) == 0)
                dpart[(size_t)(blockIdx.x * 2 + wc) * Mtot + blockIdx.z * 1024 + t] = s;
        }
    }
}

// ---------- out[r,:] = bf16 num'[r,:] / (eps + sum_p dpart[p][r]) ----------

__global__ __launch_bounds__(256)
void scale_kernel(const unsigned short* __restrict__ nmb, float* __restrict__ out,
                  const float* __restrict__ dpart, int Mtot) {
    int r = blockIdx.x;
    float s = 1e-6f;
    #pragma unroll
    for (int p = 0; p < 16; ++p) s += dpart[(size_t)p * Mtot + r];
    float inv = 1.f / s;
    const uint2* src = reinterpret_cast<const uint2*>(nmb + (size_t)r * 1024);
    float4* dst = reinterpret_cast<float4*>(out + (size_t)r * 1024);
    uint2 u = src[threadIdx.x];
    float4 v = { bf2f((unsigned short)(u.x & 0xffff)) * inv,
                 bf2f((unsigned short)(u.x >> 16))    * inv,
                 bf2f((unsigned short)(u.y & 0xffff)) * inv,
                 bf2f((unsigned short)(u.y >> 16))    * inv };
    dst[threadIdx.x] = v;
}

// ---------- launch ----------

extern "C" void kernel_launch(void* const* d_in, const int* in_sizes, int n_in,
                              void* d_out, int out_size, void* d_ws, size_t ws_size,
                              hipStream_t stream) {
    const float* x     = (const float*)d_in[0];
    const float* gamma = (const float*)d_in[1];
    const float* Wq    = (const float*)d_in[2];
    const float* bq    = (const float*)d_in[3];
    const float* Wk    = (const float*)d_in[4];
    const float* bk    = (const float*)d_in[5];
    const float* Wv    = (const float*)d_in[6];
    const float* bv    = (const float*)d_in[7];
    float* out = (float*)d_out;

    const int D = 1024, T = 1024;
    const int B = in_sizes[0] / (T * D);
    const int M = B * T;  // 4096

    char* ws = (char*)d_ws;
    size_t off = 0;
    unsigned short* xb  = (unsigned short*)(ws + off); off += (size_t)M * D * 2;      // 8 MB
    unsigned short* wqk = (unsigned short*)(ws + off); off += (size_t)2 * D * D * 2;  // 4 MB
    unsigned short* qb  = (unsigned short*)(ws + off); off += (size_t)M * D * 2;      // 8 MB
    unsigned short* kb  = (unsigned short*)(ws + off); off += (size_t)M * D * 2;      // 8 MB
    float* vd    = (float*)(ws + off); off += (size_t)M * 4;                          // 16 KB
    float* dpart = (float*)(ws + off); off += (size_t)16 * M * 4;                     // 256 KB
    unsigned short* nmb = xb;  // xb dead after gemm_qk; reuse as bf16 num' scratch

    const int n4x = M * D / 4, n4w = D * D / 4;

    // 1. pack x, Wq, Wk -> bf16
    pack3_kernel<<<dim3((n4x + 2 * n4w) / 256), 256, 0, stream>>>(x, Wq, Wk, xb, wqk, n4x, n4w);

    // 2. v diagonal (reads bf16 xb)
    vdiag_kernel<<<dim3(M / 4), 256, 0, stream>>>(xb, Wv, bv, vd);

    // 3. q = relu(x Wq^T + bq), k = relu(x Wk^T + bk); 256x128 tile, 8 waves
    gemm_qk_kernel<<<dim3(2048 / 128, M / 256), 512, 0, stream>>>(
        xb, wqk, qb, kb, bq, bk, D);

    // 4. QK GEMM fused: nmb = bf16(C*vd*QK), dpart = denom partials
    gemm_attn_kernel<<<dim3(T / 128, T / 128, B), 256, 0, stream>>>(
        qb, kb, nmb, vd, dpart, gamma, D, M);

    // 5. out = num' / denom
    scale_kernel<<<dim3(M), 256, 0, stream>>>(nmb, out, dpart, M);
}

// Round 6
// 76.233 us; speedup vs baseline: 1.1784x; 1.1071x over previous
//
#include <hip/hip_runtime.h>

typedef __attribute__((ext_vector_type(8))) short bf16x8;
typedef __attribute__((ext_vector_type(4))) float f32x4;

// ---------- helpers ----------

__device__ __forceinline__ unsigned short f2bf(float f) {
    unsigned int u = __builtin_bit_cast(unsigned int, f);
    u += 0x7fffu + ((u >> 16) & 1u);
    return (unsigned short)(u >> 16);
}

__device__ __forceinline__ float bf2f(unsigned short s) {
    return __builtin_bit_cast(float, (unsigned int)s << 16);
}

__device__ __forceinline__ void g2lds16(const unsigned short* g, unsigned short* l) {
    __builtin_amdgcn_global_load_lds(
        (const __attribute__((address_space(1))) unsigned int*)g,
        (__attribute__((address_space(3))) unsigned int*)l, 16, 0, 0);
}

// ---------- pack x, Wq, Wk -> bf16 in one dispatch ----------

__global__ __launch_bounds__(256)
void pack3_kernel(const float* __restrict__ x, const float* __restrict__ wq,
                  const float* __restrict__ wk, unsigned short* __restrict__ xb,
                  unsigned short* __restrict__ wqk, int n4x, int n4w) {
    int i = blockIdx.x * 256 + threadIdx.x;
    const float* src; unsigned short* dst; int idx;
    if (i < n4x)            { src = x;  dst = xb;  idx = i; }
    else if (i < n4x + n4w) { src = wq; dst = wqk; idx = i - n4x; }
    else                    { src = wk; dst = wqk + (size_t)n4w * 4; idx = i - n4x - n4w; }
    float4 v = reinterpret_cast<const float4*>(src)[idx];
    union { unsigned short s[4]; uint2 u; } o;
    o.s[0] = f2bf(v.x); o.s[1] = f2bf(v.y); o.s[2] = f2bf(v.z); o.s[3] = f2bf(v.w);
    reinterpret_cast<uint2*>(dst)[idx] = o.u;
}

// ---------- vd[b*T+j] = dot(xb[b,j,:], Wv[j,:]) + bv[j] ----------

__global__ __launch_bounds__(256)
void vdiag_kernel(const unsigned short* __restrict__ xb, const float* __restrict__ Wv,
                  const float* __restrict__ bv, float* __restrict__ vd) {
    int w = blockIdx.x * 4 + (threadIdx.x >> 6);
    int lane = threadIdx.x & 63;
    int b = w >> 10, j = w & 1023;
    const unsigned short* xr = xb + (size_t)(b * 1024 + j) * 1024;
    const float* wr = Wv + (size_t)j * 1024;
    float s = 0.f;
    #pragma unroll
    for (int e = 0; e < 2; ++e) {
        int base = e * 512 + lane * 8;
        bf16x8 xv = *reinterpret_cast<const bf16x8*>(xr + base);
        float4 w0 = *reinterpret_cast<const float4*>(wr + base);
        float4 w1 = *reinterpret_cast<const float4*>(wr + base + 4);
        s = fmaf(bf2f((unsigned short)xv[0]), w0.x, s);
        s = fmaf(bf2f((unsigned short)xv[1]), w0.y, s);
        s = fmaf(bf2f((unsigned short)xv[2]), w0.z, s);
        s = fmaf(bf2f((unsigned short)xv[3]), w0.w, s);
        s = fmaf(bf2f((unsigned short)xv[4]), w1.x, s);
        s = fmaf(bf2f((unsigned short)xv[5]), w1.y, s);
        s = fmaf(bf2f((unsigned short)xv[6]), w1.z, s);
        s = fmaf(bf2f((unsigned short)xv[7]), w1.w, s);
    }
    #pragma unroll
    for (int off = 32; off; off >>= 1) s += __shfl_down(s, off, 64);
    if (lane == 0) vd[w] = s + bv[j];
}

// ---------- q/k GEMM: 128x64 tile, 256 threads, 2-phase dbuf ----------
// A = xb (M x 1024), B = wqk (2048 x 1024), NT. col<1024 -> qb (relu+bq),
// col>=1024 -> kb (relu+bk), bf16 out. Grid (2048/64, M/128) = 32 x 32 = 1024.

__global__ __launch_bounds__(256, 4)
void gemm_qk_kernel(const unsigned short* __restrict__ A, const unsigned short* __restrict__ Bm,
                    unsigned short* __restrict__ qb, unsigned short* __restrict__ kb,
                    const float* __restrict__ bq, const float* __restrict__ bk, int K) {
    __shared__ unsigned short lA[2][128 * 32];
    __shared__ unsigned short lB[2][64 * 32];

    const int tid = threadIdx.x;
    const int lane = tid & 63;
    const int wid = tid >> 6;
    const int wr = wid >> 1;            // 0..1 (64-row stripe)
    const int wc = wid & 1;             // 0..1 (32-col stripe)
    const int tileM = blockIdx.y * 128, tileN = blockIdx.x * 64;

    const int r0 = tid >> 2;            // rows 0..63 / 0..127 for A
    const int r1 = (tid + 256) >> 2;
    const int cc = (tid & 3) * 8;
    const int frow = lane & 15;
    const int fk = (lane >> 4) * 8;

    f32x4 acc[4][2];
    #pragma unroll
    for (int m = 0; m < 4; ++m)
        #pragma unroll
        for (int n = 0; n < 2; ++n)
            acc[m][n] = (f32x4){0.f, 0.f, 0.f, 0.f};

    auto stage = [&](int buf, int k0) {
        g2lds16(A + (size_t)(tileM + r0) * K + (k0 + cc), &lA[buf][tid * 8]);
        g2lds16(A + (size_t)(tileM + r1) * K + (k0 + cc), &lA[buf][2048 + tid * 8]);
        g2lds16(Bm + (size_t)(tileN + r0) * K + (k0 + cc), &lB[buf][tid * 8]);
    };

    stage(0, 0);
    __syncthreads();
    int cur = 0;
    for (int k0 = 0; k0 < K; k0 += 32) {
        if (k0 + 32 < K) stage(cur ^ 1, k0 + 32);

        bf16x8 af[4], bfr[2];
        #pragma unroll
        for (int m = 0; m < 4; ++m)
            af[m] = *reinterpret_cast<const bf16x8*>(&lA[cur][(wr * 64 + m * 16 + frow) * 32 + fk]);
        #pragma unroll
        for (int n = 0; n < 2; ++n)
            bfr[n] = *reinterpret_cast<const bf16x8*>(&lB[cur][(wc * 32 + n * 16 + frow) * 32 + fk]);

        #pragma unroll
        for (int m = 0; m < 4; ++m)
            #pragma unroll
            for (int n = 0; n < 2; ++n)
                acc[m][n] = __builtin_amdgcn_mfma_f32_16x16x32_bf16(af[m], bfr[n], acc[m][n], 0, 0, 0);

        __syncthreads();
        cur ^= 1;
    }

    const int orow = (lane >> 4) * 4;
    const int ocol = lane & 15;
    const bool isQ = tileN < 1024;
    unsigned short* Cq = isQ ? qb : kb;
    const float* bias = isQ ? bq : bk;
    const int cb = tileN - (isQ ? 0 : 1024);

    #pragma unroll
    for (int n = 0; n < 2; ++n) {
        int col = cb + wc * 32 + n * 16 + ocol;
        float bia = bias[col];
        #pragma unroll
        for (int m = 0; m < 4; ++m) {
            #pragma unroll
            for (int i = 0; i < 4; ++i) {
                int row = tileM + wr * 64 + m * 16 + orow + i;
                float v = acc[m][n][i] + bia;
                Cq[(size_t)row * 1024 + col] = f2bf(v > 0.f ? v : 0.f);
            }
        }
    }
}

// ---------- QK GEMM (per batch), 64x128 tile, fused C-weight/vd epilogue ----------
// A = qb[z], B = kb[z]. num' = C(t,j)*vd*QK -> bf16 nmb[z];
// dpart[(bx*2+wc)*Mtot + z*1024 + t] = denom partials.
// Grid (1024/128, 1024/64, B) = (8, 16, 4) = 512 blocks.

__global__ __launch_bounds__(256, 2)
void gemm_attn_kernel(const unsigned short* __restrict__ A, const unsigned short* __restrict__ Bm,
                      unsigned short* __restrict__ nmb, const float* __restrict__ vd,
                      float* __restrict__ dpart, const float* __restrict__ gammap,
                      int K, int Mtot) {
    __shared__ unsigned short lA[2][64 * 32];
    __shared__ unsigned short lB[2][128 * 32];

    const int tid = threadIdx.x;
    const int lane = tid & 63;
    const int wid = tid >> 6;
    const int wr = wid >> 1, wc = wid & 1;
    const int tileM = blockIdx.y * 64, tileN = blockIdx.x * 128;

    const unsigned short* Ab = A + (size_t)blockIdx.z * 1024 * 1024;
    const unsigned short* Bb = Bm + (size_t)blockIdx.z * 1024 * 1024;

    const int r0 = tid >> 2;            // 0..63
    const int r1 = (tid + 256) >> 2;    // 64..127 (B only)
    const int cc = (tid & 3) * 8;
    const int frow = lane & 15;
    const int fk = (lane >> 4) * 8;

    f32x4 acc[2][4];
    #pragma unroll
    for (int m = 0; m < 2; ++m)
        #pragma unroll
        for (int n = 0; n < 4; ++n)
            acc[m][n] = (f32x4){0.f, 0.f, 0.f, 0.f};

    auto stage = [&](int buf, int k0) {
        g2lds16(Ab + (size_t)(tileM + r0) * K + (k0 + cc), &lA[buf][tid * 8]);
        g2lds16(Bb + (size_t)(tileN + r0) * K + (k0 + cc), &lB[buf][tid * 8]);
        g2lds16(Bb + (size_t)(tileN + r1) * K + (k0 + cc), &lB[buf][2048 + tid * 8]);
    };

    stage(0, 0);
    __syncthreads();
    int cur = 0;
    for (int k0 = 0; k0 < K; k0 += 32) {
        if (k0 + 32 < K) stage(cur ^ 1, k0 + 32);

        bf16x8 af[2], bfr[4];
        #pragma unroll
        for (int m = 0; m < 2; ++m)
            af[m] = *reinterpret_cast<const bf16x8*>(&lA[cur][(wr * 32 + m * 16 + frow) * 32 + fk]);
        #pragma unroll
        for (int n = 0; n < 4; ++n)
            bfr[n] = *reinterpret_cast<const bf16x8*>(&lB[cur][(wc * 64 + n * 16 + frow) * 32 + fk]);

        #pragma unroll
        for (int m = 0; m < 2; ++m)
            #pragma unroll
            for (int n = 0; n < 4; ++n)
                acc[m][n] = __builtin_amdgcn_mfma_f32_16x16x32_bf16(af[m], bfr[n], acc[m][n], 0, 0, 0);

        __syncthreads();
        cur ^= 1;
    }

    const int orow = (lane >> 4) * 4;
    const int ocol = lane & 15;

    unsigned short* ob = nmb + (size_t)blockIdx.z * 1024 * 1024;
    const float* vdb = vd + blockIdx.z * 1024;
    const float g = gammap[0];
    const float l2g = log2f(g);
    const float inv1mg = 1.f / (1.f - g);
    const float c1 = g * inv1mg;

    int jcol[4]; float gj[4], vdv[4];
    #pragma unroll
    for (int n = 0; n < 4; ++n) {
        jcol[n] = tileN + wc * 64 + n * 16 + ocol;
        gj[n] = exp2f((float)jcol[n] * l2g);
        vdv[n] = vdb[jcol[n]];
    }

    #pragma unroll
    for (int m = 0; m < 2; ++m) {
        #pragma unroll
        for (int i = 0; i < 4; ++i) {
            int t = tileM + wr * 32 + m * 16 + orow + i;
            float gt = exp2f((float)t * l2g);
            float ctf = (1.f - g * gt) * inv1mg;
            float s = 0.f;
            #pragma unroll
            for (int n = 0; n < 4; ++n) {
                int j = jcol[n];
                float Cfut = exp2f((float)(j - t) * l2g) * ctf;        // j > t
                float Cpast = (float)(t - j + 1) + c1 * (1.f - gj[n]); // j <= t
                float Cw = (j <= t) ? Cpast : Cfut;
                float v = acc[m][n][i];
                s += Cw * v;
                ob[(size_t)t * 1024 + j] = f2bf(Cw * vdv[n] * v);
            }
            s += __shfl_xor(s, 1, 64);
            s += __shfl_xor(s, 2, 64);
            s += __shfl_xor(s, 4, 64);
            s += __shfl_xor(s, 8, 64);
            if ((lane & 15) == 0)
                dpart[(size_t)(blockIdx.x * 2 + wc) * Mtot + blockIdx.z * 1024 + t] = s;
        }
    }
}

// ---------- out[r,:] = bf16 num'[r,:] / (eps + sum_p dpart[p][r]) ----------

__global__ __launch_bounds__(256)
void scale_kernel(const unsigned short* __restrict__ nmb, float* __restrict__ out,
                  const float* __restrict__ dpart, int Mtot) {
    int r = blockIdx.x;
    float s = 1e-6f;
    #pragma unroll
    for (int p = 0; p < 16; ++p) s += dpart[(size_t)p * Mtot + r];
    float inv = 1.f / s;
    const uint2* src = reinterpret_cast<const uint2*>(nmb + (size_t)r * 1024);
    float4* dst = reinterpret_cast<float4*>(out + (size_t)r * 1024);
    uint2 u = src[threadIdx.x];
    float4 v = { bf2f((unsigned short)(u.x & 0xffff)) * inv,
                 bf2f((unsigned short)(u.x >> 16))    * inv,
                 bf2f((unsigned short)(u.y & 0xffff)) * inv,
                 bf2f((unsigned short)(u.y >> 16))    * inv };
    dst[threadIdx.x] = v;
}

// ---------- launch ----------

extern "C" void kernel_launch(void* const* d_in, const int* in_sizes, int n_in,
                              void* d_out, int out_size, void* d_ws, size_t ws_size,
                              hipStream_t stream) {
    const float* x     = (const float*)d_in[0];
    const float* gamma = (const float*)d_in[1];
    const float* Wq    = (const float*)d_in[2];
    const float* bq    = (const float*)d_in[3];
    const float* Wk    = (const float*)d_in[4];
    const float* bk    = (const float*)d_in[5];
    const float* Wv    = (const float*)d_in[6];
    const float* bv    = (const float*)d_in[7];
    float* out = (float*)d_out;

    const int D = 1024, T = 1024;
    const int B = in_sizes[0] / (T * D);
    const int M = B * T;  // 4096

    char* ws = (char*)d_ws;
    size_t off = 0;
    unsigned short* xb  = (unsigned short*)(ws + off); off += (size_t)M * D * 2;      // 8 MB
    unsigned short* wqk = (unsigned short*)(ws + off); off += (size_t)2 * D * D * 2;  // 4 MB
    unsigned short* qb  = (unsigned short*)(ws + off); off += (size_t)M * D * 2;      // 8 MB
    unsigned short* kb  = (unsigned short*)(ws + off); off += (size_t)M * D * 2;      // 8 MB
    float* vd    = (float*)(ws + off); off += (size_t)M * 4;                          // 16 KB
    float* dpart = (float*)(ws + off); off += (size_t)16 * M * 4;                     // 256 KB
    unsigned short* nmb = xb;  // xb dead after gemm_qk; reuse as bf16 num' scratch

    const int n4x = M * D / 4, n4w = D * D / 4;

    // 1. pack x, Wq, Wk -> bf16
    pack3_kernel<<<dim3((n4x + 2 * n4w) / 256), 256, 0, stream>>>(x, Wq, Wk, xb, wqk, n4x, n4w);

    // 2. v diagonal (reads bf16 xb)
    vdiag_kernel<<<dim3(M / 4), 256, 0, stream>>>(xb, Wv, bv, vd);

    // 3. q = relu(x Wq^T + bq), k = relu(x Wk^T + bk); 128x64 tiles, 1024 blocks
    gemm_qk_kernel<<<dim3(2048 / 64, M / 128), 256, 0, stream>>>(
        xb, wqk, qb, kb, bq, bk, D);

    // 4. QK GEMM fused: nmb = bf16(C*vd*QK), dpart; 64x128 tiles, 512 blocks
    gemm_attn_kernel<<<dim3(T / 128, T / 64, B), 256, 0, stream>>>(
        qb, kb, nmb, vd, dpart, gamma, D, M);

    // 5. out = num' / denom
    scale_kernel<<<dim3(M), 256, 0, stream>>>(nmb, out, dpart, M);
}